// Round 1
// baseline (98.640 us; speedup 1.0000x reference)
//
#include <hip/hip_runtime.h>

// Fast Walsh-Hadamard Transform along last dim (4096), scale 1/64.
// x: (rows, 4096) f32  ->  y: (rows, 4096) f32, y = FWHT(x)/64 == x @ H.

constexpr int DIMV = 4096;

// Bijective float4-slot swizzle: XOR low-3 slot bits with slot bits 4..6.
// Keeps 16B alignment; makes all our LDS access patterns <=2 lanes/bank.
__device__ __forceinline__ int swz(int s) { return s ^ ((s >> 4) & 7); }

__device__ __forceinline__ void bf(float& a, float& b) {
    float t = a + b;
    b = a - b;
    a = t;
}

__device__ __forceinline__ void bf4(float4& a, float4& b) {
    bf(a.x, b.x); bf(a.y, b.y); bf(a.z, b.z); bf(a.w, b.w);
}

__device__ __forceinline__ void fwht16(float (&w)[16]) {
#pragma unroll
    for (int s = 1; s < 16; s <<= 1) {
#pragma unroll
        for (int i = 0; i < 16; ++i) {
            if ((i & s) == 0) bf(w[i], w[i | s]);
        }
    }
}

__global__ __launch_bounds__(256) void fwht4096_kernel(const float* __restrict__ x,
                                                       float* __restrict__ y) {
    __shared__ __align__(16) float lds[DIMV];
    const int tid = threadIdx.x;
    const long long row = blockIdx.x;

    const float4* xr = reinterpret_cast<const float4*>(x) + row * (DIMV / 4);
    float4*       yr = reinterpret_cast<float4*>(y)       + row * (DIMV / 4);
    float4*       l4 = reinterpret_cast<float4*>(lds);

    // ---- Load: thread holds elements d = 4*tid + k + 1024*q (k in float4, q=0..3)
    float4 v[4];
#pragma unroll
    for (int q = 0; q < 4; ++q) v[q] = xr[tid + 256 * q];

    const float sc = 0.015625f;  // 1/64 = 1/sqrt(4096)
#pragma unroll
    for (int q = 0; q < 4; ++q) { v[q].x *= sc; v[q].y *= sc; v[q].z *= sc; v[q].w *= sc; }

    // ---- Phase 1: element bits {0,1} (within float4) and {10,11} (across q)
#pragma unroll
    for (int q = 0; q < 4; ++q) {
        bf(v[q].x, v[q].y); bf(v[q].z, v[q].w);   // bit 0 (stride 1)
        bf(v[q].x, v[q].z); bf(v[q].y, v[q].w);   // bit 1 (stride 2)
    }
    bf4(v[0], v[1]); bf4(v[2], v[3]);             // bit 10 (stride 1024)
    bf4(v[0], v[2]); bf4(v[1], v[3]);             // bit 11 (stride 2048)

    // ---- To LDS (swizzled slots), b128 writes, conflict-free
#pragma unroll
    for (int q = 0; q < 4; ++q) l4[swz(tid + 256 * q)] = v[q];
    __syncthreads();

    // ---- Phase 2: element bits {2..5}. d = k + 4*j + 64*h
    {
        const int k = tid & 3;
        const int h = tid >> 2;  // element bits 6..11
        float w[16];
#pragma unroll
        for (int j = 0; j < 16; ++j) w[j] = lds[4 * swz(j + 16 * h) + k];
        fwht16(w);
#pragma unroll
        for (int j = 0; j < 16; ++j) lds[4 * swz(j + 16 * h) + k] = w[j];
    }
    __syncthreads();

    // ---- Phase 3: element bits {6..9}. d = k + 4*c + 64*m + 1024*u
    {
        const int k = tid & 3;
        const int c = (tid >> 2) & 15;  // element bits 2..5
        const int u = tid >> 6;         // element bits 10,11
        float w[16];
#pragma unroll
        for (int m = 0; m < 16; ++m) w[m] = lds[4 * swz(c + 16 * m + 256 * u) + k];
        fwht16(w);
#pragma unroll
        for (int m = 0; m < 16; ++m) lds[4 * swz(c + 16 * m + 256 * u) + k] = w[m];
    }
    __syncthreads();

    // ---- Store: b128 reads in load pattern, coalesced float4 global stores
#pragma unroll
    for (int q = 0; q < 4; ++q) yr[tid + 256 * q] = l4[swz(tid + 256 * q)];
}

extern "C" void kernel_launch(void* const* d_in, const int* in_sizes, int n_in,
                              void* d_out, int out_size, void* d_ws, size_t ws_size,
                              hipStream_t stream) {
    const float* x = (const float*)d_in[0];
    float* y = (float*)d_out;
    const int rows = in_sizes[0] / DIMV;  // 4 * 4096 = 16384
    dim3 grid(rows), block(256);
    hipLaunchKernelGGL(fwht4096_kernel, grid, block, 0, stream, x, y);
}